// Round 5
// baseline (499.194 us; speedup 1.0000x reference)
//
#include <hip/hip_runtime.h>

#define C 128
#define NN 50000      // N_USER == N_ITEM
#define NP 50048      // padded rows: 391 * 128
#define NE 600000
#define LN_EPS 1e-5f
#define NBKT 782      // buckets per edge type: ceil(50000/64)
#define BPAD 1024
#define CHUNK 4096
#define NCHUNK ((NE + CHUNK - 1) / CHUNK)   // 147
#define CAP 1280      // bucket capacity (avg 768, +18 sigma)

typedef __attribute__((ext_vector_type(8))) short short8;
typedef __attribute__((ext_vector_type(4))) float f32x4;
typedef __attribute__((ext_vector_type(2))) float f32x2;
typedef unsigned short u16;
typedef unsigned int u32;

union V16 { uint4 u; short8 s; };

__device__ inline f32x2 bf2f2(u32 v) {
  union { u32 i; float f; } lo, hi;
  lo.i = v << 16; hi.i = v & 0xffff0000u;
  f32x2 r; r.x = lo.f; r.y = hi.f; return r;     // -> v_lshl + v_and + v_pk_add_f32 at use
}
__device__ inline u16 f2bf(float f) {
  union { float f; u32 i; } x; x.f = f;
  u32 r = (x.i + 0x7fffu + ((x.i >> 16) & 1u)) >> 16;   // RNE
  return (u16)r;
}

// ---------------- fused setup: bucket binning (blocks 0..3*NCHUNK) + prep (rest) -----
// bin: groups edges by dst bucket (dst>>6); payload u32 = (dl<<16)|src.
// prep: fp32->bf16 features + weight concat/pack.
// Wu[c][k]: k<128 Wl_iu; 128..255 Wr_iu+Wr_uu; 256..383 Wl_uu   (Ktot=384)
// Wi[c][k]: k<128 Wl_ui; 128..255 Wr_ui                          (Ktot=256)
struct SetupArgs {
  const int *e0, *e1, *e2;
  u32* bdata; int* cursor;
  const float *xu, *xi;
  const float *Wl_iu[2], *Wr_iu[2], *Wr_uu[2], *Wl_uu[2], *Wl_ui[2], *Wr_ui[2];
  const float *b_iu[2], *b_uu[2], *b_ui[2];
  u16 *xb_u, *xb_i;
  u16 *Wu[2], *Wi[2];
  float *bu[2], *bi[2];
};
#define PK (128 * 384 + 128 * 256 + 256)
#define BINB (3 * NCHUNK)

__global__ __launch_bounds__(256) void setup_kernel(SetupArgs a) {
  __shared__ u32 stage[CHUNK];     // 16 KB
  __shared__ int histk[BPAD];      // hist, then startk (overwritten in place)
  __shared__ int fillc[BPAD];
  __shared__ int gbase[BPAD];
  __shared__ int wsum[4];
  int tid = threadIdx.x;
  if (blockIdx.x < BINB) {
    int lane = tid & 63, wv = tid >> 6;
    int t = blockIdx.x / NCHUNK, ck = blockIdx.x % NCHUNK;
    const int* ei  = (t == 0) ? a.e0 : (t == 1) ? a.e1 : a.e2;
    const int* src = ei;
    const int* dst = ei + NE;
    int base = ck * CHUNK;
    int cnt = min(CHUNK, NE - base);
    for (int i = tid; i < BPAD; i += 256) histk[i] = 0;
    __syncthreads();
    for (int k = tid; k < cnt; k += 256)
      atomicAdd(&histk[dst[base + k] >> 6], 1);
    __syncthreads();
    // exclusive scan (thread owns 4 bins); histk becomes startk
    int h0 = histk[tid * 4], h1 = histk[tid * 4 + 1], h2 = histk[tid * 4 + 2], h3 = histk[tid * 4 + 3];
    int s = h0 + h1 + h2 + h3;
    int incl = s;
    #pragma unroll
    for (int d = 1; d < 64; d <<= 1) { int x = __shfl_up(incl, d, 64); if (lane >= d) incl += x; }
    if (lane == 63) wsum[wv] = incl;
    __syncthreads();
    int wbase = 0;
    for (int w = 0; w < wv; w++) wbase += wsum[w];
    int excl = wbase + incl - s;
    histk[tid * 4]     = excl;
    histk[tid * 4 + 1] = excl + h0;
    histk[tid * 4 + 2] = excl + h0 + h1;
    histk[tid * 4 + 3] = excl + h0 + h1 + h2;
    int hv[4] = { h0, h1, h2, h3 };
    #pragma unroll
    for (int j = 0; j < 4; j++) {
      int b = tid * 4 + j;
      fillc[b] = histk[b];
      gbase[b] = (hv[j] > 0 && b < NBKT) ? atomicAdd(&a.cursor[t * NBKT + b], hv[j]) : 0;
    }
    __syncthreads();
    for (int k = tid; k < cnt; k += 256) {
      int d = dst[base + k], sv = src[base + k];
      int b = d >> 6;
      int slot = atomicAdd(&fillc[b], 1);
      stage[slot] = ((u32)b << 22) | ((u32)(d & 63) << 16) | (u32)sv;
    }
    __syncthreads();
    for (int i = tid; i < cnt; i += 256) {
      u32 u = stage[i];
      int b = u >> 22;
      int pos = gbase[b] + (i - histk[b]);
      if (pos < CAP)
        a.bdata[(size_t)(t * NBKT + b) * CAP + pos] = u & 0x3fffff;
    }
    return;
  }
  // ---- prep part ----
  const int n4 = NN * C / 4;
  int id = (blockIdx.x - BINB) * 256 + tid;
  if (id < 2 * n4) {
    int second = id >= n4;
    int j = second ? id - n4 : id;
    float4 v = ((const float4*)(second ? a.xi : a.xu))[j];
    ushort4 o = make_ushort4(f2bf(v.x), f2bf(v.y), f2bf(v.z), f2bf(v.w));
    ((ushort4*)(second ? a.xb_i : a.xb_u))[j] = o;
    return;
  }
  int id2 = id - 2 * n4;
  if (id2 >= 2 * PK) return;
  int l = id2 / PK, j = id2 % PK;
  const int NU = 128 * 384, NI = 128 * 256;
  if (j < NU) {
    int c = j / 384, k = j % 384;
    float v = (k < 128) ? a.Wl_iu[l][c * 128 + k]
            : (k < 256) ? (a.Wr_iu[l][c * 128 + k - 128] + a.Wr_uu[l][c * 128 + k - 128])
                        : a.Wl_uu[l][c * 128 + k - 256];
    a.Wu[l][j] = f2bf(v);
  } else if (j < NU + NI) {
    int q = j - NU;
    int c = q / 256, k = q % 256;
    float v = (k < 128) ? a.Wl_ui[l][c * 128 + k] : a.Wr_ui[l][c * 128 + k - 128];
    a.Wi[l][q] = f2bf(v);
  } else {
    int q = j - NU - NI;
    if (q < 128) a.bu[l][q] = a.b_iu[l][q] + a.b_uu[l][q];
    else a.bi[l][q - 128] = a.b_ui[l][q - 128];
  }
}

// ---------------- sort-once: counting sort + degree-sorted run table -----------------
// Runs ONCE per bench iteration (edges are layer-invariant). Output written IN PLACE
// into the bucket's bdata slot:
//   bytes [0, CAP*2)        : sorted src ids as u16 (src < 65536)
//   bytes [CAP*2, CAP*2+256): 64 run-info words, rank-ordered by descending length:
//                             (dl<<22) | (beg<<11) | len
// Rank-ordering gives quarter-waves near-equal run lengths in the fused gather.
__global__ __launch_bounds__(256) void sort_buckets(
    u32* __restrict__ bdata, const int* __restrict__ cursor) {
  __shared__ u32 stage[CAP];
  __shared__ u16 ords[CAP];
  __shared__ int hist[64];
  __shared__ int boff[65];
  __shared__ int fillc[64];
  __shared__ int lens[64];
  int tid = threadIdx.x;
  int id = blockIdx.x;                   // 0..3*NBKT-1
  int cnt = min(cursor[id], CAP);
  u32* bkt = bdata + (size_t)id * CAP;
  if (tid < 64) hist[tid] = 0;
  __syncthreads();
  for (int i = tid; i < cnt; i += 256) {
    u32 u = bkt[i];
    stage[i] = u;
    atomicAdd(&hist[(u >> 16) & 63], 1);
  }
  __syncthreads();
  if (tid < 64) {                        // wave 0: exclusive scan over 64 bins
    int v = hist[tid];
    int incl = v;
    #pragma unroll
    for (int d = 1; d < 64; d <<= 1) {
      int x = __shfl_up(incl, d, 64);
      if (tid >= d) incl += x;
    }
    boff[tid + 1] = incl;
    if (tid == 0) boff[0] = 0;
    fillc[tid] = incl - v;
    lens[tid] = v;
  }
  __syncthreads();
  for (int i = tid; i < cnt; i += 256) {
    u32 u = stage[i];
    int slot = atomicAdd(&fillc[(u >> 16) & 63], 1);
    ords[slot] = (u16)u;
  }
  if (tid < 64) {                        // stable rank by descending run length
    int L = lens[tid];
    int r = 0;
    for (int j = 0; j < 64; j++) {
      int Lj = lens[j];
      r += (Lj > L || (Lj == L && j < tid)) ? 1 : 0;
    }
    bkt[(CAP >> 1) + r] = ((u32)tid << 22) | ((u32)boff[tid] << 11) | (u32)L;
  }
  __syncthreads();
  int cnt2 = (cnt + 1) >> 1;
  for (int i = tid; i < cnt2; i += 256)  // coalesced copy-out of sorted srcs
    bkt[i] = ((const u32*)ords)[i];
}

// ---------------- fused layer: gather-to-LDS + MFMA GEMM + LayerNorm + ReLU ---------
// gridDim = (391, 2). Block (x, y) consumes exactly mean buckets {2x, 2x+1} of its
// edge types, so aggregation runs inline: gather edge means directly into the LDS
// A-tile Am[128][136] (same layout as Wt; conflict-free b128 reads), never touching
// global mean buffers (-76 MB round-trip vs the split version). y==0 item side
// (seg0=mean_ui from xu, seg1=self xb_i; Ktot=256); y==1 user side (seg0=mean_iu
// from xi, seg2=mean_uu from xu, seg1=self xb_u; Ktot=384). Zero-length runs write
// zero rows (empty dst => mean 0). 2 blocks/CU: one block's gather (memory) overlaps
// the other's MFMA (matrix pipe). Gather is fabric-limited, not occupancy-limited
// (r0/r2/r3: 62-73% occ all pin at 3.4-3.6 TB/s), so 8 waves/CU sustains it.
struct FusedArgs {
  const u16 *xu, *xi;                 // current layer input tables (NP rows)
  const u32* bdata; const int* cursor;
  const u16 *Wi; const float *bi, *lnwi, *lnbi; float* outfi; u16* outbi;
  const u16 *Wu; const float *bu, *lnwu, *lnbu; float* outfu; u16* outbu;
};

__global__ __launch_bounds__(256) void fused_layer(FusedArgs g) {
  __shared__ u16 Wt[128][136];        // 34.8 KB
  __shared__ u16 Am[128][136];        // 34.8 KB
  __shared__ u16 ords[2 * CAP];       // 5 KB
  __shared__ u32 rinf[2][64];
  int tid = threadIdx.x, lane = tid & 63, wv = tid >> 6;
  int arow = lane & 15, kq = (lane >> 4) * 8;
  int x = blockIdx.x, user = blockIdx.y;
  int n0 = x * 128 + wv * 32;

  const u16 *W, *self;
  const float *bias, *lnw, *lnb; float* outf; u16* outb;
  int Ktot;
  if (user) { W = g.Wu; bias = g.bu; lnw = g.lnwu; lnb = g.lnbu;
              outf = g.outfu; outb = g.outbu; self = g.xu; Ktot = 384; }
  else      { W = g.Wi; bias = g.bi; lnw = g.lnwi; lnb = g.lnbi;
              outf = g.outfi; outb = g.outbi; self = g.xi; Ktot = 256; }

  // T14: self A-fragments + epilogue params issued early, consumed late
  const u16* Sr0 = self + (size_t)(n0 + arow) * C + kq;
  const u16* Sr1 = self + (size_t)(n0 + 16 + arow) * C + kq;
  V16 a0[4], a1[4];
  #pragma unroll
  for (int c4 = 0; c4 < 4; c4++) {
    a0[c4].u = *(const uint4*)(Sr0 + c4 * 32);
    a1[c4].u = *(const uint4*)(Sr1 + c4 * 32);
  }
  float bv[8], lnwv[8], lnbv[8];
  #pragma unroll
  for (int t = 0; t < 8; t++) {
    int c = t * 16 + arow;
    bv[t] = bias[c]; lnwv[t] = lnw[c]; lnbv[t] = lnb[c];
  }
  f32x4 acc[2][8];
  #pragma unroll
  for (int gg = 0; gg < 2; gg++)
    #pragma unroll
    for (int t = 0; t < 8; t++) acc[gg][t] = (f32x4){0.f, 0.f, 0.f, 0.f};

  auto load_ords = [&](int ts) {
    #pragma unroll
    for (int kb = 0; kb < 2; kb++) {
      int id = ts * NBKT + 2 * x + kb;
      int cnt = min(g.cursor[id], CAP);
      const u32* bkt = g.bdata + (size_t)id * CAP;
      for (int i = tid; i < ((cnt + 1) >> 1); i += 256)
        ((u32*)(ords + kb * CAP))[i] = bkt[i];
      if (tid < 64) rinf[kb][tid] = bkt[(CAP >> 1) + tid];
    }
  };

  auto gather = [&](const u16* xs) {     // 2 buckets -> Am rows [0,128)
    int qw = tid >> 4, ql = tid & 15;
    const uint4* xsv = (const uint4*)xs;
    #pragma unroll
    for (int kb = 0; kb < 2; kb++) {
      const u16* od = ords + kb * CAP;
      #pragma unroll
      for (int gr = 0; gr < 4; gr++) {
        u32 ri = rinf[kb][gr * 16 + qw];
        int dl  = (int)(ri >> 22);
        int beg = (int)((ri >> 11) & 0x7ffu);
        int len = (int)(ri & 0x7ffu);
        int end = beg + len;
        f32x2 s0 = {0.f, 0.f}, s1 = {0.f, 0.f}, s2 = {0.f, 0.f}, s3 = {0.f, 0.f};
        int e = beg;
        for (; e + 8 <= end; e += 8) {   // 8 gathers in flight per quarter-wave
          uint4 v0 = xsv[(u32)od[e]     * 16u + (u32)ql];
          uint4 v1 = xsv[(u32)od[e + 1] * 16u + (u32)ql];
          uint4 v2 = xsv[(u32)od[e + 2] * 16u + (u32)ql];
          uint4 v3 = xsv[(u32)od[e + 3] * 16u + (u32)ql];
          uint4 v4 = xsv[(u32)od[e + 4] * 16u + (u32)ql];
          uint4 v5 = xsv[(u32)od[e + 5] * 16u + (u32)ql];
          uint4 v6 = xsv[(u32)od[e + 6] * 16u + (u32)ql];
          uint4 v7 = xsv[(u32)od[e + 7] * 16u + (u32)ql];
          s0 += bf2f2(v0.x); s1 += bf2f2(v0.y); s2 += bf2f2(v0.z); s3 += bf2f2(v0.w);
          s0 += bf2f2(v1.x); s1 += bf2f2(v1.y); s2 += bf2f2(v1.z); s3 += bf2f2(v1.w);
          s0 += bf2f2(v2.x); s1 += bf2f2(v2.y); s2 += bf2f2(v2.z); s3 += bf2f2(v2.w);
          s0 += bf2f2(v3.x); s1 += bf2f2(v3.y); s2 += bf2f2(v3.z); s3 += bf2f2(v3.w);
          s0 += bf2f2(v4.x); s1 += bf2f2(v4.y); s2 += bf2f2(v4.z); s3 += bf2f2(v4.w);
          s0 += bf2f2(v5.x); s1 += bf2f2(v5.y); s2 += bf2f2(v5.z); s3 += bf2f2(v5.w);
          s0 += bf2f2(v6.x); s1 += bf2f2(v6.y); s2 += bf2f2(v6.z); s3 += bf2f2(v6.w);
          s0 += bf2f2(v7.x); s1 += bf2f2(v7.y); s2 += bf2f2(v7.z); s3 += bf2f2(v7.w);
        }
        if (e + 4 <= end) {
          uint4 v0 = xsv[(u32)od[e]     * 16u + (u32)ql];
          uint4 v1 = xsv[(u32)od[e + 1] * 16u + (u32)ql];
          uint4 v2 = xsv[(u32)od[e + 2] * 16u + (u32)ql];
          uint4 v3 = xsv[(u32)od[e + 3] * 16u + (u32)ql];
          s0 += bf2f2(v0.x); s1 += bf2f2(v0.y); s2 += bf2f2(v0.z); s3 += bf2f2(v0.w);
          s0 += bf2f2(v1.x); s1 += bf2f2(v1.y); s2 += bf2f2(v1.z); s3 += bf2f2(v1.w);
          s0 += bf2f2(v2.x); s1 += bf2f2(v2.y); s2 += bf2f2(v2.z); s3 += bf2f2(v2.w);
          s0 += bf2f2(v3.x); s1 += bf2f2(v3.y); s2 += bf2f2(v3.z); s3 += bf2f2(v3.w);
          e += 4;
        }
        for (; e < end; e++) {
          uint4 v0 = xsv[(u32)od[e] * 16u + (u32)ql];
          s0 += bf2f2(v0.x); s1 += bf2f2(v0.y); s2 += bf2f2(v0.z); s3 += bf2f2(v0.w);
        }
        float inv = 1.0f / fmaxf((float)len, 1.0f);
        uint4 o;
        o.x = (u32)f2bf(s0.x * inv) | ((u32)f2bf(s0.y * inv) << 16);
        o.y = (u32)f2bf(s1.x * inv) | ((u32)f2bf(s1.y * inv) << 16);
        o.z = (u32)f2bf(s2.x * inv) | ((u32)f2bf(s2.y * inv) << 16);
        o.w = (u32)f2bf(s3.x * inv) | ((u32)f2bf(s3.y * inv) << 16);
        *(uint4*)&Am[kb * 64 + dl][ql * 8] = o;   // zero rows for empty dsts
      }
    }
  };

  auto stageW = [&](int sg) {
    #pragma unroll
    for (int it = 0; it < 8; it++) {
      int chunk = it * 256 + tid;
      int c = chunk >> 4, k8 = (chunk & 15) * 8;
      *(uint4*)&Wt[c][k8] = *(const uint4*)(W + (size_t)c * Ktot + sg * 128 + k8);
    }
  };

  auto mfma_lds = [&]() {               // A from Am
    #pragma unroll
    for (int c4 = 0; c4 < 4; c4++) {
      V16 A0, A1;
      A0.u = *(const uint4*)&Am[wv * 32 + arow][kq + c4 * 32];
      A1.u = *(const uint4*)&Am[wv * 32 + 16 + arow][kq + c4 * 32];
      #pragma unroll
      for (int t = 0; t < 8; t++) {
        short8 bfr = *(const short8*)&Wt[t * 16 + arow][kq + c4 * 32];
        acc[0][t] = __builtin_amdgcn_mfma_f32_16x16x32_bf16(A0.s, bfr, acc[0][t], 0, 0, 0);
        acc[1][t] = __builtin_amdgcn_mfma_f32_16x16x32_bf16(A1.s, bfr, acc[1][t], 0, 0, 0);
      }
    }
  };

  // ---- schedule ----
  load_ords(user ? 1 : 0);
  __syncthreads();                      // ords/rinf ready
  gather(user ? g.xi : g.xu);
  stageW(0);
  __syncthreads();                      // Am + Wt seg0 ready
  mfma_lds();                           // mean segment 0
  if (user) {
    load_ords(2);                       // safe: gathers done before previous barrier
    __syncthreads();                    // ords t2 ready; Am/Wt readers done
    gather(g.xu);
    stageW(2);
    __syncthreads();
    mfma_lds();                         // mean segment 2 (uu)
  }
  __syncthreads();                      // Wt readers done
  stageW(1);
  __syncthreads();
  #pragma unroll
  for (int c4 = 0; c4 < 4; c4++) {      // self segment (regs loaded at kernel start)
    #pragma unroll
    for (int t = 0; t < 8; t++) {
      short8 bfr = *(const short8*)&Wt[t * 16 + arow][kq + c4 * 32];
      acc[0][t] = __builtin_amdgcn_mfma_f32_16x16x32_bf16(a0[c4].s, bfr, acc[0][t], 0, 0, 0);
      acc[1][t] = __builtin_amdgcn_mfma_f32_16x16x32_bf16(a1[c4].s, bfr, acc[1][t], 0, 0, 0);
    }
  }

  // ---- LayerNorm + ReLU epilogue ----
  #pragma unroll
  for (int gg = 0; gg < 2; gg++) {
    #pragma unroll
    for (int r = 0; r < 4; r++) {
      float s1 = 0.f, s2 = 0.f;
      #pragma unroll
      for (int t = 0; t < 8; t++) {
        float v = acc[gg][t][r] + bv[t];
        s1 += v; s2 += v * v;
      }
      #pragma unroll
      for (int d = 1; d < 16; d <<= 1) {
        s1 += __shfl_xor(s1, d, 64);
        s2 += __shfl_xor(s2, d, 64);
      }
      float mu = s1 * (1.f / 128.f);
      float var = s2 * (1.f / 128.f) - mu * mu;
      float rs = rsqrtf(var + LN_EPS);
      int gr = n0 + gg * 16 + (lane >> 4) * 4 + r;
      if (gr < NN) {
        #pragma unroll
        for (int t = 0; t < 8; t++) {
          float y = (acc[gg][t][r] + bv[t] - mu) * rs * lnwv[t] + lnbv[t];
          y = fmaxf(y, 0.f);
          int c = t * 16 + arow;
          if (outf) outf[(size_t)gr * C + c] = y;
          else      outb[(size_t)gr * C + c] = f2bf(y);
        }
      }
    }
  }
}

extern "C" void kernel_launch(void* const* d_in, const int* in_sizes, int n_in,
                              void* d_out, int out_size, void* d_ws, size_t ws_size,
                              hipStream_t stream) {
  const float* xu = (const float*)d_in[0];
  const float* xi = (const float*)d_in[1];
  const int* ei[3] = { (const int*)d_in[2], (const int*)d_in[3], (const int*)d_in[4] };
  const float* P[26];
  for (int k = 0; k < 26; k++) P[k] = (const float*)d_in[5 + k];
  // per layer l, Q = P+13l: [0]Wl_ui [1]b_ui [2]Wr_ui [3]Wl_iu [4]b_iu [5]Wr_iu
  //                         [6]Wl_uu [7]b_uu [8]Wr_uu [9]lnw_u [10]lnb_u [11]lnw_i [12]lnb_i

  // ---- workspace (~64 MB; no global mean buffers anymore) ----
  char* p = (char*)d_ws;
  auto alloc = [&](size_t bytes) { char* r = p; p += (bytes + 255) & ~(size_t)255; return r; };
  u32* bdata  = (u32*)alloc((size_t)3 * NBKT * CAP * 4);
  int* cursor = (int*)alloc((size_t)3 * NBKT * 4);
  u16* xb_u  = (u16*)alloc((size_t)NP * C * 2);
  u16* xb_i  = (u16*)alloc((size_t)NP * C * 2);
  u16* xb2_u = (u16*)alloc((size_t)NP * C * 2);   // layer-0 output (no in-place:
  u16* xb2_i = (u16*)alloc((size_t)NP * C * 2);   // gather+gemm share a dispatch)
  u16 *Wu[2], *Wi[2]; float *bu[2], *bi[2];
  for (int l = 0; l < 2; l++) {
    Wu[l] = (u16*)alloc(128 * 384 * 2);
    Wi[l] = (u16*)alloc(128 * 256 * 2);
    bu[l] = (float*)alloc(128 * 4);
    bi[l] = (float*)alloc(128 * 4);
  }

  // ---- fused setup: binning + bf16 converts + weight packs ----
  hipMemsetAsync(cursor, 0, (size_t)3 * NBKT * 4, stream);
  SetupArgs sa;
  sa.e0 = ei[0]; sa.e1 = ei[1]; sa.e2 = ei[2];
  sa.bdata = bdata; sa.cursor = cursor;
  sa.xu = xu; sa.xi = xi; sa.xb_u = xb_u; sa.xb_i = xb_i;
  for (int l = 0; l < 2; l++) {
    const float* const* Q = P + 13 * l;
    sa.Wl_iu[l] = Q[3]; sa.Wr_iu[l] = Q[5]; sa.Wr_uu[l] = Q[8]; sa.Wl_uu[l] = Q[6];
    sa.Wl_ui[l] = Q[0]; sa.Wr_ui[l] = Q[2];
    sa.b_iu[l] = Q[4]; sa.b_uu[l] = Q[7]; sa.b_ui[l] = Q[1];
    sa.Wu[l] = Wu[l]; sa.Wi[l] = Wi[l]; sa.bu[l] = bu[l]; sa.bi[l] = bi[l];
  }
  const int n4 = NN * C / 4;
  const int prep_blocks = (2 * n4 + 2 * PK + 255) / 256;
  setup_kernel<<<BINB + prep_blocks, 256, 0, stream>>>(sa);

  // ---- sort once (edges are layer-invariant) ----
  sort_buckets<<<3 * NBKT, 256, 0, stream>>>(bdata, cursor);

  for (int l = 0; l < 2; l++) {
    const float* const* Q = P + 13 * l;
    FusedArgs f;
    f.xu = (l == 0) ? xb_u : xb2_u;
    f.xi = (l == 0) ? xb_i : xb2_i;
    f.bdata = bdata; f.cursor = cursor;
    f.Wi = Wi[l]; f.bi = bi[l]; f.lnwi = Q[11]; f.lnbi = Q[12];
    f.Wu = Wu[l]; f.bu = bu[l]; f.lnwu = Q[9]; f.lnbu = Q[10];
    if (l == 0) {
      f.outfi = nullptr; f.outbi = xb2_i;
      f.outfu = nullptr; f.outbu = xb2_u;
    } else {
      f.outfi = (float*)d_out + (size_t)NN * C; f.outbi = nullptr;
      f.outfu = (float*)d_out;                  f.outbu = nullptr;
    }
    fused_layer<<<dim3(NP / 128, 2), 256, 0, stream>>>(f);
  }
  (void)in_sizes; (void)n_in; (void)out_size; (void)ws_size;
}

// Round 6
// 365.321 us; speedup vs baseline: 1.3665x; 1.3665x over previous
//
#include <hip/hip_runtime.h>

#define C 128
#define NN 50000      // N_USER == N_ITEM
#define NP 50048      // padded rows: 391 * 128
#define NE 600000
#define LN_EPS 1e-5f
#define NBKT 782      // buckets per edge type: ceil(50000/64)
#define BPAD 1024
#define CHUNK 4096
#define NCHUNK ((NE + CHUNK - 1) / CHUNK)   // 147
#define CAP 1280      // bucket capacity (avg 768, +18 sigma)
#define AGG_J 313
#define AGG_GRID (8 * AGG_J)   // 2504: type-major XCD-partitioned agg grid

typedef __attribute__((ext_vector_type(8))) short short8;
typedef __attribute__((ext_vector_type(4))) float f32x4;
typedef __attribute__((ext_vector_type(2))) float f32x2;
typedef unsigned short u16;
typedef unsigned int u32;

union V16 { uint4 u; short8 s; };

__device__ inline f32x2 bf2f2(u32 v) {
  union { u32 i; float f; } lo, hi;
  lo.i = v << 16; hi.i = v & 0xffff0000u;
  f32x2 r; r.x = lo.f; r.y = hi.f; return r;     // -> v_lshl + v_and + v_pk_add_f32 at use
}
__device__ inline u16 f2bf(float f) {
  union { float f; u32 i; } x; x.f = f;
  u32 r = (x.i + 0x7fffu + ((x.i >> 16) & 1u)) >> 16;   // RNE
  return (u16)r;
}

// Type-major XCD partition for aggregation (bid%8 ~ XCD under round-robin dispatch):
// XCDs 0..4 process xu-reading buckets (t0: ids [0,NBKT), t2: ids [2*NBKT,3*NBKT)),
// XCDs 5..7 process xi-reading buckets (t1: ids [NBKT,2*NBKT)). Halves each XCD's
// gather working set 25.6 MB -> 12.8 MB vs its 4 MB L2 (r4: 41% L2 miss on 460 MB).
// Mapping-independent correctness: bijective onto bucket ids, idle blocks return.
__device__ inline int remap_bucket(int bid) {
  int s = bid & 7, j = bid >> 3;
  if (s < 5) {
    int g = j * 5 + s;                  // [0, 2*NBKT) covered (5*313=1565 >= 1564)
    if (g >= 2 * NBKT) return -1;
    return (g < NBKT) ? g : g + NBKT;   // t0, then t2
  } else {
    int g = j * 3 + (s - 5);            // [0, NBKT) covered (3*313=939 >= 782)
    if (g >= NBKT) return -1;
    return NBKT + g;                    // t1
  }
}

// ---------------- fused setup: bucket binning (blocks 0..3*NCHUNK) + prep (rest) -----
// bin: groups edges by dst bucket (dst>>6); payload u32 = (dl<<16)|src.
// prep: fp32->bf16 features + weight concat/pack.
// Wu[c][k]: k<128 Wl_iu; 128..255 Wr_iu+Wr_uu; 256..383 Wl_uu   (Ktot=384)
// Wi[c][k]: k<128 Wl_ui; 128..255 Wr_ui                          (Ktot=256)
struct SetupArgs {
  const int *e0, *e1, *e2;
  u32* bdata; int* cursor;
  const float *xu, *xi;
  const float *Wl_iu[2], *Wr_iu[2], *Wr_uu[2], *Wl_uu[2], *Wl_ui[2], *Wr_ui[2];
  const float *b_iu[2], *b_uu[2], *b_ui[2];
  u16 *xb_u, *xb_i;
  u16 *Wu[2], *Wi[2];
  float *bu[2], *bi[2];
};
#define PK (128 * 384 + 128 * 256 + 256)
#define BINB (3 * NCHUNK)

__global__ __launch_bounds__(256) void setup_kernel(SetupArgs a) {
  __shared__ u32 stage[CHUNK];     // 16 KB
  __shared__ int histk[BPAD];      // hist, then startk (overwritten in place)
  __shared__ int fillc[BPAD];
  __shared__ int gbase[BPAD];
  __shared__ int wsum[4];
  int tid = threadIdx.x;
  if (blockIdx.x < BINB) {
    int lane = tid & 63, wv = tid >> 6;
    int t = blockIdx.x / NCHUNK, ck = blockIdx.x % NCHUNK;
    const int* ei  = (t == 0) ? a.e0 : (t == 1) ? a.e1 : a.e2;
    const int* src = ei;
    const int* dst = ei + NE;
    int base = ck * CHUNK;
    int cnt = min(CHUNK, NE - base);
    for (int i = tid; i < BPAD; i += 256) histk[i] = 0;
    __syncthreads();
    for (int k = tid; k < cnt; k += 256)
      atomicAdd(&histk[dst[base + k] >> 6], 1);
    __syncthreads();
    // exclusive scan (thread owns 4 bins); histk becomes startk
    int h0 = histk[tid * 4], h1 = histk[tid * 4 + 1], h2 = histk[tid * 4 + 2], h3 = histk[tid * 4 + 3];
    int s = h0 + h1 + h2 + h3;
    int incl = s;
    #pragma unroll
    for (int d = 1; d < 64; d <<= 1) { int x = __shfl_up(incl, d, 64); if (lane >= d) incl += x; }
    if (lane == 63) wsum[wv] = incl;
    __syncthreads();
    int wbase = 0;
    for (int w = 0; w < wv; w++) wbase += wsum[w];
    int excl = wbase + incl - s;
    histk[tid * 4]     = excl;
    histk[tid * 4 + 1] = excl + h0;
    histk[tid * 4 + 2] = excl + h0 + h1;
    histk[tid * 4 + 3] = excl + h0 + h1 + h2;
    int hv[4] = { h0, h1, h2, h3 };
    #pragma unroll
    for (int j = 0; j < 4; j++) {
      int b = tid * 4 + j;
      fillc[b] = histk[b];
      gbase[b] = (hv[j] > 0 && b < NBKT) ? atomicAdd(&a.cursor[t * NBKT + b], hv[j]) : 0;
    }
    __syncthreads();
    for (int k = tid; k < cnt; k += 256) {
      int d = dst[base + k], sv = src[base + k];
      int b = d >> 6;
      int slot = atomicAdd(&fillc[b], 1);
      stage[slot] = ((u32)b << 22) | ((u32)(d & 63) << 16) | (u32)sv;
    }
    __syncthreads();
    for (int i = tid; i < cnt; i += 256) {
      u32 u = stage[i];
      int b = u >> 22;
      int pos = gbase[b] + (i - histk[b]);
      if (pos < CAP)
        a.bdata[(size_t)(t * NBKT + b) * CAP + pos] = u & 0x3fffff;
    }
    return;
  }
  // ---- prep part ----
  const int n4 = NN * C / 4;
  int id = (blockIdx.x - BINB) * 256 + tid;
  if (id < 2 * n4) {
    int second = id >= n4;
    int j = second ? id - n4 : id;
    float4 v = ((const float4*)(second ? a.xi : a.xu))[j];
    ushort4 o = make_ushort4(f2bf(v.x), f2bf(v.y), f2bf(v.z), f2bf(v.w));
    ((ushort4*)(second ? a.xb_i : a.xb_u))[j] = o;
    return;
  }
  int id2 = id - 2 * n4;
  if (id2 >= 2 * PK) return;
  int l = id2 / PK, j = id2 % PK;
  const int NU = 128 * 384, NI = 128 * 256;
  if (j < NU) {
    int c = j / 384, k = j % 384;
    float v = (k < 128) ? a.Wl_iu[l][c * 128 + k]
            : (k < 256) ? (a.Wr_iu[l][c * 128 + k - 128] + a.Wr_uu[l][c * 128 + k - 128])
                        : a.Wl_uu[l][c * 128 + k - 256];
    a.Wu[l][j] = f2bf(v);
  } else if (j < NU + NI) {
    int q = j - NU;
    int c = q / 256, k = q % 256;
    float v = (k < 128) ? a.Wl_ui[l][c * 128 + k] : a.Wr_ui[l][c * 128 + k - 128];
    a.Wi[l][q] = f2bf(v);
  } else {
    int q = j - NU - NI;
    if (q < 128) a.bu[l][q] = a.b_iu[l][q] + a.b_uu[l][q];
    else a.bi[l][q - 128] = a.b_ui[l][q - 128];
  }
}

// ---------------- shared gather core: balanced runs, unroll-8, full-row uint4 --------
// 16 quarter-waves x 16 lanes; each quarter-wave walks 4 rank-stratified runs.
// ords: sorted src ids (u16, LDS); rinf: rank-ordered (dl<<22)|(beg<<11)|len (LDS).
__device__ __forceinline__ void gather_accum(
    const u16* __restrict__ ords, const u32* __restrict__ rinf,
    const u16* __restrict__ xs, u16* __restrict__ mean, int b, int tid) {
  int qw = tid >> 4, ql = tid & 15;
  const uint4* xsv = (const uint4*)xs;   // row r, lane ql -> xsv[r*16 + ql]
  #pragma unroll
  for (int g = 0; g < 4; g++) {
    u32 ri = rinf[g * 16 + qw];
    int dl  = (int)(ri >> 22);
    int beg = (int)((ri >> 11) & 0x7ffu);
    int len = (int)(ri & 0x7ffu);
    int end = beg + len;
    f32x2 s0 = {0.f, 0.f}, s1 = {0.f, 0.f}, s2 = {0.f, 0.f}, s3 = {0.f, 0.f};
    int e = beg;
    for (; e + 8 <= end; e += 8) {       // 8 gathers in flight per quarter-wave
      uint4 v0 = xsv[(u32)ords[e]     * 16u + (u32)ql];
      uint4 v1 = xsv[(u32)ords[e + 1] * 16u + (u32)ql];
      uint4 v2 = xsv[(u32)ords[e + 2] * 16u + (u32)ql];
      uint4 v3 = xsv[(u32)ords[e + 3] * 16u + (u32)ql];
      uint4 v4 = xsv[(u32)ords[e + 4] * 16u + (u32)ql];
      uint4 v5 = xsv[(u32)ords[e + 5] * 16u + (u32)ql];
      uint4 v6 = xsv[(u32)ords[e + 6] * 16u + (u32)ql];
      uint4 v7 = xsv[(u32)ords[e + 7] * 16u + (u32)ql];
      s0 += bf2f2(v0.x); s1 += bf2f2(v0.y); s2 += bf2f2(v0.z); s3 += bf2f2(v0.w);
      s0 += bf2f2(v1.x); s1 += bf2f2(v1.y); s2 += bf2f2(v1.z); s3 += bf2f2(v1.w);
      s0 += bf2f2(v2.x); s1 += bf2f2(v2.y); s2 += bf2f2(v2.z); s3 += bf2f2(v2.w);
      s0 += bf2f2(v3.x); s1 += bf2f2(v3.y); s2 += bf2f2(v3.z); s3 += bf2f2(v3.w);
      s0 += bf2f2(v4.x); s1 += bf2f2(v4.y); s2 += bf2f2(v4.z); s3 += bf2f2(v4.w);
      s0 += bf2f2(v5.x); s1 += bf2f2(v5.y); s2 += bf2f2(v5.z); s3 += bf2f2(v5.w);
      s0 += bf2f2(v6.x); s1 += bf2f2(v6.y); s2 += bf2f2(v6.z); s3 += bf2f2(v6.w);
      s0 += bf2f2(v7.x); s1 += bf2f2(v7.y); s2 += bf2f2(v7.z); s3 += bf2f2(v7.w);
    }
    if (e + 4 <= end) {
      uint4 v0 = xsv[(u32)ords[e]     * 16u + (u32)ql];
      uint4 v1 = xsv[(u32)ords[e + 1] * 16u + (u32)ql];
      uint4 v2 = xsv[(u32)ords[e + 2] * 16u + (u32)ql];
      uint4 v3 = xsv[(u32)ords[e + 3] * 16u + (u32)ql];
      s0 += bf2f2(v0.x); s1 += bf2f2(v0.y); s2 += bf2f2(v0.z); s3 += bf2f2(v0.w);
      s0 += bf2f2(v1.x); s1 += bf2f2(v1.y); s2 += bf2f2(v1.z); s3 += bf2f2(v1.w);
      s0 += bf2f2(v2.x); s1 += bf2f2(v2.y); s2 += bf2f2(v2.z); s3 += bf2f2(v2.w);
      s0 += bf2f2(v3.x); s1 += bf2f2(v3.y); s2 += bf2f2(v3.z); s3 += bf2f2(v3.w);
      e += 4;
    }
    for (; e < end; e++) {
      uint4 v0 = xsv[(u32)ords[e] * 16u + (u32)ql];
      s0 += bf2f2(v0.x); s1 += bf2f2(v0.y); s2 += bf2f2(v0.z); s3 += bf2f2(v0.w);
    }
    int n = b * 64 + dl;
    if (n < NN) {
      float inv = 1.0f / fmaxf((float)len, 1.0f);
      uint4 o;
      o.x = (u32)f2bf(s0.x * inv) | ((u32)f2bf(s0.y * inv) << 16);
      o.y = (u32)f2bf(s1.x * inv) | ((u32)f2bf(s1.y * inv) << 16);
      o.z = (u32)f2bf(s2.x * inv) | ((u32)f2bf(s2.y * inv) << 16);
      o.w = (u32)f2bf(s3.x * inv) | ((u32)f2bf(s3.y * inv) << 16);
      *(uint4*)(mean + (size_t)n * C + ql * 8) = o;
    }
  }
}

// ---------------- layer-0 aggregation: fused counting sort + gather ------------------
// Sorts edges by dst-local id in LDS (hidden under gather stalls), writes packed u16
// srcs + rank-ordered run table back into the bucket's bdata slot for layer-1, then
// gathers. Type-major XCD remap (see remap_bucket).
__global__ __launch_bounds__(256) void aggregate_sort(
    u16* __restrict__ mA, u16* __restrict__ mB, u16* __restrict__ mC,
    const u16* __restrict__ xu, const u16* __restrict__ xi,
    u32* __restrict__ bdata, const int* __restrict__ cursor) {
  __shared__ u32 stage[CAP];
  __shared__ u16 ords[CAP];
  __shared__ u32 rinf[64];
  __shared__ int hist[64];
  __shared__ int boff[65];
  __shared__ int fillc[64];
  __shared__ int lens[64];
  int tid = threadIdx.x;
  int id = remap_bucket(blockIdx.x);
  if (id < 0) return;                    // idle pad block (uniform across block)
  int t = id / NBKT, b = id - t * NBKT;
  const u16* xs = (t == 1) ? xi : xu;
  u16* mean = (t == 0) ? mA : (t == 1) ? mB : mC;
  int cnt = min(cursor[id], CAP);
  u32* bkt = bdata + (size_t)id * CAP;
  if (tid < 64) hist[tid] = 0;
  __syncthreads();
  for (int i = tid; i < cnt; i += 256) {
    u32 u = bkt[i];
    stage[i] = u;
    atomicAdd(&hist[(u >> 16) & 63], 1);
  }
  __syncthreads();
  if (tid < 64) {                        // wave 0: exclusive scan over 64 bins
    int v = hist[tid];
    int incl = v;
    #pragma unroll
    for (int d = 1; d < 64; d <<= 1) {
      int x = __shfl_up(incl, d, 64);
      if (tid >= d) incl += x;
    }
    boff[tid + 1] = incl;
    if (tid == 0) boff[0] = 0;
    fillc[tid] = incl - v;
    lens[tid] = v;
  }
  __syncthreads();
  for (int i = tid; i < cnt; i += 256) {
    u32 u = stage[i];
    int slot = atomicAdd(&fillc[(u >> 16) & 63], 1);
    ords[slot] = (u16)u;
  }
  if (tid < 64) {                        // stable rank by descending run length
    int L = lens[tid];
    int r = 0;
    for (int j = 0; j < 64; j++) {
      int Lj = lens[j];
      r += (Lj > L || (Lj == L && j < tid)) ? 1 : 0;
    }
    u32 ri = ((u32)tid << 22) | ((u32)boff[tid] << 11) | (u32)L;
    rinf[r] = ri;
    bkt[(CAP >> 1) + r] = ri;            // run table for layer-1 fast path
  }
  __syncthreads();
  int cnt2 = (cnt + 1) >> 1;
  for (int i = tid; i < cnt2; i += 256)  // packed srcs for layer-1 (hides under gather)
    bkt[i] = ((const u32*)ords)[i];
  gather_accum(ords, rinf, xs, mean, b, tid);
}

// ---------------- layer-1 aggregation: pure gather on pre-sorted buckets ------------
__global__ __launch_bounds__(256) void aggregate_fast(
    u16* __restrict__ mA, u16* __restrict__ mB, u16* __restrict__ mC,
    const u16* __restrict__ xu, const u16* __restrict__ xi,
    const u32* __restrict__ bdata, const int* __restrict__ cursor) {
  __shared__ u16 ords[CAP];
  __shared__ u32 rinf[64];
  int tid = threadIdx.x;
  int id = remap_bucket(blockIdx.x);
  if (id < 0) return;                    // idle pad block
  int t = id / NBKT, b = id - t * NBKT;
  const u16* xs = (t == 1) ? xi : xu;
  u16* mean = (t == 0) ? mA : (t == 1) ? mB : mC;
  int cnt = min(cursor[id], CAP);
  const u32* bkt = bdata + (size_t)id * CAP;
  int cnt2 = (cnt + 1) >> 1;
  for (int i = tid; i < cnt2; i += 256) ((u32*)ords)[i] = bkt[i];
  if (tid < 64) rinf[tid] = bkt[(CAP >> 1) + tid];
  __syncthreads();
  gather_accum(ords, rinf, xs, mean, b, tid);
}

// ---------------- fused MFMA GEMM (+bias) + LayerNorm + ReLU, both node types -------
// gridDim = (391, 2): y==0 item side (nseg=2, Ktot=256), y==1 user side (nseg=3, Ktot=384).
// BM=128 (4 waves x 32 rows), BN=128. W K-segment staged in LDS (136-u16 rows).
// A-fragment global loads issued BEFORE W staging (T14 issue-early).
struct GemmArgs {
  const u16 *Ai0, *Ai1;
  const u16 *Wi; const float *bi, *lnwi, *lnbi; float* outfi; u16* outbi;
  const u16 *Au0, *Au1, *Au2;
  const u16 *Wu; const float *bu, *lnwu, *lnbu; float* outfu; u16* outbu;
};
__global__ __launch_bounds__(256) void gemm2_ln_relu(GemmArgs g) {
  __shared__ u16 Wt[128][136];
  int tid = threadIdx.x, lane = tid & 63, wv = tid >> 6;
  int arow = lane & 15, kq = (lane >> 4) * 8;
  int n0 = blockIdx.x * 128 + wv * 32;
  int user = blockIdx.y;
  const u16* As[3];
  const u16* W; const float *bias, *lnw, *lnb; float* outf; u16* outb;
  int nseg, Ktot;
  if (user) {
    As[0] = g.Au0; As[1] = g.Au1; As[2] = g.Au2; nseg = 3; Ktot = 384;
    W = g.Wu; bias = g.bu; lnw = g.lnwu; lnb = g.lnbu; outf = g.outfu; outb = g.outbu;
  } else {
    As[0] = g.Ai0; As[1] = g.Ai1; As[2] = nullptr; nseg = 2; Ktot = 256;
    W = g.Wi; bias = g.bi; lnw = g.lnwi; lnb = g.lnbi; outf = g.outfi; outb = g.outbi;
  }
  float bv[8], lnwv[8], lnbv[8];
  #pragma unroll
  for (int t = 0; t < 8; t++) {          // hoisted epilogue params: in flight early
    int c = t * 16 + arow;
    bv[t] = bias[c]; lnwv[t] = lnw[c]; lnbv[t] = lnb[c];
  }
  f32x4 acc[2][8];
  #pragma unroll
  for (int gg = 0; gg < 2; gg++)
    #pragma unroll
    for (int t = 0; t < 8; t++) acc[gg][t] = (f32x4){0.f, 0.f, 0.f, 0.f};

  for (int sg = 0; sg < nseg; sg++) {
    // ---- issue A-fragment loads first (independent of LDS) ----
    const u16* Ar0 = As[sg] + (size_t)(n0 + arow) * C + kq;
    const u16* Ar1 = As[sg] + (size_t)(n0 + 16 + arow) * C + kq;
    V16 a0[4], a1[4];
    #pragma unroll
    for (int c4 = 0; c4 < 4; c4++) {
      a0[c4].u = *(const uint4*)(Ar0 + c4 * 32);
      a1[c4].u = *(const uint4*)(Ar1 + c4 * 32);
    }
    __syncthreads();                     // prev segment's Wt readers done
    #pragma unroll
    for (int it = 0; it < 8; it++) {            // stage 128x128 W segment (32 KB)
      int chunk = it * 256 + tid;
      int c = chunk >> 4, k8 = (chunk & 15) * 8;
      uint4 v = *(const uint4*)(W + (size_t)c * Ktot + sg * 128 + k8);
      *(uint4*)&Wt[c][k8] = v;
    }
    __syncthreads();
    #pragma unroll
    for (int c4 = 0; c4 < 4; c4++) {
      #pragma unroll
      for (int t = 0; t < 8; t++) {
        short8 bfr = *(const short8*)&Wt[t * 16 + arow][kq + c4 * 32];
        acc[0][t] = __builtin_amdgcn_mfma_f32_16x16x32_bf16(a0[c4].s, bfr, acc[0][t], 0, 0, 0);
        acc[1][t] = __builtin_amdgcn_mfma_f32_16x16x32_bf16(a1[c4].s, bfr, acc[1][t], 0, 0, 0);
      }
    }
  }
  #pragma unroll
  for (int gg = 0; gg < 2; gg++) {
    #pragma unroll
    for (int r = 0; r < 4; r++) {
      float s1 = 0.f, s2 = 0.f;
      #pragma unroll
      for (int t = 0; t < 8; t++) {
        float v = acc[gg][t][r] + bv[t];
        s1 += v; s2 += v * v;
      }
      #pragma unroll
      for (int d = 1; d < 16; d <<= 1) {
        s1 += __shfl_xor(s1, d, 64);
        s2 += __shfl_xor(s2, d, 64);
      }
      float mu = s1 * (1.f / 128.f);
      float var = s2 * (1.f / 128.f) - mu * mu;
      float rs = rsqrtf(var + LN_EPS);
      int gr = n0 + gg * 16 + (lane >> 4) * 4 + r;
      if (gr < NN) {
        #pragma unroll
        for (int t = 0; t < 8; t++) {
          float y = (acc[gg][t][r] + bv[t] - mu) * rs * lnwv[t] + lnbv[t];
          y = fmaxf(y, 0.f);
          int c = t * 16 + arow;
          if (outf) outf[(size_t)gr * C + c] = y;
          else      outb[(size_t)gr * C + c] = f2bf(y);
        }
      }
    }
  }
}

extern "C" void kernel_launch(void* const* d_in, const int* in_sizes, int n_in,
                              void* d_out, int out_size, void* d_ws, size_t ws_size,
                              hipStream_t stream) {
  const float* xu = (const float*)d_in[0];
  const float* xi = (const float*)d_in[1];
  const int* ei[3] = { (const int*)d_in[2], (const int*)d_in[3], (const int*)d_in[4] };
  const float* P[26];
  for (int k = 0; k < 26; k++) P[k] = (const float*)d_in[5 + k];
  // per layer l, Q = P+13l: [0]Wl_ui [1]b_ui [2]Wr_ui [3]Wl_iu [4]b_iu [5]Wr_iu
  //                         [6]Wl_uu [7]b_uu [8]Wr_uu [9]lnw_u [10]lnb_u [11]lnw_i [12]lnb_i

  // ---- workspace (~77 MB; sorted edge lists + run tables alias into bdata) ----
  char* p = (char*)d_ws;
  auto alloc = [&](size_t bytes) { char* r = p; p += (bytes + 255) & ~(size_t)255; return r; };
  u32* bdata  = (u32*)alloc((size_t)3 * NBKT * CAP * 4);
  int* cursor = (int*)alloc((size_t)3 * NBKT * 4);
  u16* xb_u  = (u16*)alloc((size_t)NP * C * 2);
  u16* xb_i  = (u16*)alloc((size_t)NP * C * 2);
  u16* meanA = (u16*)alloc((size_t)NP * C * 2);
  u16* meanB = (u16*)alloc((size_t)NP * C * 2);
  u16* meanC = (u16*)alloc((size_t)NP * C * 2);
  u16 *Wu[2], *Wi[2]; float *bu[2], *bi[2];
  for (int l = 0; l < 2; l++) {
    Wu[l] = (u16*)alloc(128 * 384 * 2);
    Wi[l] = (u16*)alloc(128 * 256 * 2);
    bu[l] = (float*)alloc(128 * 4);
    bi[l] = (float*)alloc(128 * 4);
  }

  // ---- fused setup: binning + bf16 converts + weight packs ----
  hipMemsetAsync(cursor, 0, (size_t)3 * NBKT * 4, stream);
  SetupArgs sa;
  sa.e0 = ei[0]; sa.e1 = ei[1]; sa.e2 = ei[2];
  sa.bdata = bdata; sa.cursor = cursor;
  sa.xu = xu; sa.xi = xi; sa.xb_u = xb_u; sa.xb_i = xb_i;
  for (int l = 0; l < 2; l++) {
    const float* const* Q = P + 13 * l;
    sa.Wl_iu[l] = Q[3]; sa.Wr_iu[l] = Q[5]; sa.Wr_uu[l] = Q[8]; sa.Wl_uu[l] = Q[6];
    sa.Wl_ui[l] = Q[0]; sa.Wr_ui[l] = Q[2];
    sa.b_iu[l] = Q[4]; sa.b_uu[l] = Q[7]; sa.b_ui[l] = Q[1];
    sa.Wu[l] = Wu[l]; sa.Wi[l] = Wi[l]; sa.bu[l] = bu[l]; sa.bi[l] = bi[l];
  }
  const int n4 = NN * C / 4;
  const int prep_blocks = (2 * n4 + 2 * PK + 255) / 256;
  setup_kernel<<<BINB + prep_blocks, 256, 0, stream>>>(sa);

  for (int l = 0; l < 2; l++) {
    const float* const* Q = P + 13 * l;
    if (l == 0)
      aggregate_sort<<<AGG_GRID, 256, 0, stream>>>(meanA, meanB, meanC, xb_u, xb_i,
                                                   bdata, cursor);
    else
      aggregate_fast<<<AGG_GRID, 256, 0, stream>>>(meanA, meanB, meanC, xb_u, xb_i,
                                                   bdata, cursor);
    GemmArgs g;
    g.Ai0 = meanA; g.Ai1 = xb_i; g.Wi = Wi[l]; g.bi = bi[l]; g.lnwi = Q[11]; g.lnbi = Q[12];
    g.Au0 = meanB; g.Au1 = xb_u; g.Au2 = meanC; g.Wu = Wu[l]; g.bu = bu[l];
    g.lnwu = Q[9]; g.lnbu = Q[10];
    if (l == 0) {
      g.outfi = nullptr; g.outbi = xb_i;   // in place (block reads only its own rows)
      g.outfu = nullptr; g.outbu = xb_u;
    } else {
      g.outfi = (float*)d_out + (size_t)NN * C; g.outbi = nullptr;
      g.outfu = (float*)d_out;                  g.outbu = nullptr;
    }
    gemm2_ln_relu<<<dim3(NP / 128, 2), 256, 0, stream>>>(g);
  }
  (void)in_sizes; (void)n_in; (void)out_size; (void)ws_size;
}